// Round 1
// baseline (105.720 us; speedup 1.0000x reference)
//
#include <hip/hip_runtime.h>
#include <hip/hip_bf16.h>

// EmbeddingShard: out[t, :] = (W_full[tok[t], :] + sum_s b[s, :]) / SHARDS
// x: [B*S]=16384 int32 tokens; W: [8, 6300, 4096] f32 (contiguous => W_full [50400,4096]);
// b: [8, 4096] f32; out: [16384, 4096] f32. Pure memory-bound gather.

#define D_MODEL 4096
#define SHARDS 8

// Step 1: bias sum (unscaled, so main kernel can do (w + bs) * 0.125f,
// matching the reference's (gather + sum_b)/8 op order; /8 is exact in fp32).
__global__ void bias_sum_kernel(const float* __restrict__ b, float* __restrict__ bs) {
    int d = blockIdx.x * blockDim.x + threadIdx.x;
    if (d < D_MODEL) {
        float s = 0.0f;
#pragma unroll
        for (int i = 0; i < SHARDS; ++i) s += b[i * D_MODEL + d];
        bs[d] = s;
    }
}

// Step 2: gather + bias + scale. One token row (4096 f32 = 1024 float4) per
// block-iteration; 256 threads x 4 float4 each, fully coalesced.
__global__ __launch_bounds__(256) void gather_kernel(const int* __restrict__ tok,
                                                     const float* __restrict__ W,
                                                     const float* __restrict__ bs,
                                                     float* __restrict__ out,
                                                     int ntok) {
    const int tid = threadIdx.x;

    // Bias fragment for this thread's 4 float4 slots (reused across tokens).
    float4 biasv[4];
    const float4* bs4 = reinterpret_cast<const float4*>(bs);
#pragma unroll
    for (int j = 0; j < 4; ++j) biasv[j] = bs4[tid + j * 256];

    for (int t = blockIdx.x; t < ntok; t += gridDim.x) {
        const int row = tok[t];
        const float4* wrow = reinterpret_cast<const float4*>(W) + (size_t)row * (D_MODEL / 4);
        float4* orow = reinterpret_cast<float4*>(out) + (size_t)t * (D_MODEL / 4);
#pragma unroll
        for (int j = 0; j < 4; ++j) {
            float4 w = wrow[tid + j * 256];
            float4 r;
            r.x = (w.x + biasv[j].x) * 0.125f;
            r.y = (w.y + biasv[j].y) * 0.125f;
            r.z = (w.z + biasv[j].z) * 0.125f;
            r.w = (w.w + biasv[j].w) * 0.125f;
            orow[tid + j * 256] = r;
        }
    }
}

extern "C" void kernel_launch(void* const* d_in, const int* in_sizes, int n_in,
                              void* d_out, int out_size, void* d_ws, size_t ws_size,
                              hipStream_t stream) {
    const int*   tok = (const int*)d_in[0];     // [16384]
    const float* W   = (const float*)d_in[1];   // [8*6300*4096] == [50400, 4096]
    const float* b   = (const float*)d_in[2];   // [8, 4096]
    float*       out = (float*)d_out;           // [16384, 4096]
    float*       bs  = (float*)d_ws;            // [4096] scratch

    const int ntok = in_sizes[0];               // B*S = 16384

    bias_sum_kernel<<<(D_MODEL + 255) / 256, 256, 0, stream>>>(b, bs);

    // 4096 blocks -> each block handles ~4 tokens; 2048 max-occupancy blocks
    // would also do, but more blocks spreads the random-row gather better.
    int grid = ntok < 4096 ? ntok : 4096;
    gather_kernel<<<grid, 256, 0, stream>>>(tok, W, bs, out, ntok);
}